// Round 10
// baseline (129.299 us; speedup 1.0000x reference)
//
#include <hip/hip_runtime.h>
#include <math.h>

#define S_LEN 2048
#define NB    2
#define CQ_   256
#define CC_   256
#define DH    50
#define KW    101
#define PS    100
#define WTH   1e-5f // phase-C weight skip threshold

#define NB2   384   // padded B-matrix width: 256 V cols + 100 hidden + 28 zero
#define MT    32    // GEMM M tile (R10: 64->32 => 768 blocks = 3/CU, no imbalance)
#define NT    64    // GEMM N tile
#define KC    32    // GEMM K chunk

// ---------------------------------------------------------------------------
// k_prep: BT[c][n] = n<256 ? Wa[c][n] : (n<356 ? Wp[n-256][c] : 0).
// (V[q] = sum_c ct[c]*Wa[c][q] -> Wa used untransposed; R8's transpose bug.)
// ---------------------------------------------------------------------------
__global__ __launch_bounds__(NB2) void k_prep(const float* __restrict__ Wa,
    const float* __restrict__ Wp, float* __restrict__ BT) {
  const int c = blockIdx.x, n = threadIdx.x;
  float v = 0.0f;
  if (n < CQ_)            v = Wa[(size_t)c * CQ_ + n];          // Wa[c][n]
  else if (n < CQ_ + PS)  v = Wp[(size_t)(n - CQ_) * CC_ + c];  // Wp[j][c]
  BT[(size_t)c * NB2 + n] = v;
}

// ---------------------------------------------------------------------------
// k_gemm: G[4096][384] = ct[4096][256] @ BT[256][384].
// 32x64 tile, 256 thr, 4x2 acc/thread, K-chunks of 32 in LDS.
// R9's 64x64 ran 384 blocks = 1.5/CU (half the CUs serialized 2 blocks, 1
// wave/SIMD, no latency cover). 768 blocks = exactly 3/CU, 12 waves/CU.
// Per k: ds_read_b128 (2 addrs/wave -> broadcast) + ds_read_b64 (2-way, free)
// + 8 FMA.
// ---------------------------------------------------------------------------
__global__ __launch_bounds__(256) void k_gemm(const float* __restrict__ ct,
    const float* __restrict__ BT, float* __restrict__ G) {
  const int bm = blockIdx.x & 127;         // 128 M tiles
  const int bn = blockIdx.x >> 7;          // 6 N tiles
  const int r0 = bm * MT;
  const int n0 = bn * NT;
  const int tid = threadIdx.x;
  const int tx = tid & 31;                 // n: 2 cols each
  const int ty = tid >> 5;                 // m: 4 rows each (0..7)

  __shared__ float As[KC][MT + 4];         // 32 x 36 (144B rows, 16B-aligned)
  __shared__ float Bs[KC][NT + 4];         // 32 x 68

  float acc[4][2];
#pragma unroll
  for (int i = 0; i < 4; ++i) { acc[i][0] = 0.0f; acc[i][1] = 0.0f; }

  const int kq = tid & 7,  mA = tid >> 3;  // A-stage: k-quad, m-row (0..31)
  const int nq = tid & 15, kB = tid >> 4;  // B-stage: n-quad, k-row (0..15)

  for (int c0 = 0; c0 < CC_; c0 += KC) {
    const float4 a0 = *(const float4*)&ct[(size_t)(r0 + mA) * CC_ + c0 + kq * 4];
    const float4 b0 = *(const float4*)&BT[(size_t)(c0 + kB) * NB2 + n0 + nq * 4];
    const float4 b1 = *(const float4*)&BT[(size_t)(c0 + kB + 16) * NB2 + n0 + nq * 4];
    __syncthreads();                       // previous chunk's reads done
    As[kq * 4 + 0][mA] = a0.x;
    As[kq * 4 + 1][mA] = a0.y;
    As[kq * 4 + 2][mA] = a0.z;
    As[kq * 4 + 3][mA] = a0.w;
    *(float4*)&Bs[kB][nq * 4]      = b0;
    *(float4*)&Bs[kB + 16][nq * 4] = b1;
    __syncthreads();
#pragma unroll
    for (int k = 0; k < KC; ++k) {         // k ascending: deterministic order
      const float4 av = *(const float4*)&As[k][ty * 4];
      const float2 bv = *(const float2*)&Bs[k][tx * 2];
      acc[0][0] = fmaf(av.x, bv.x, acc[0][0]);
      acc[0][1] = fmaf(av.x, bv.y, acc[0][1]);
      acc[1][0] = fmaf(av.y, bv.x, acc[1][0]);
      acc[1][1] = fmaf(av.y, bv.y, acc[1][1]);
      acc[2][0] = fmaf(av.z, bv.x, acc[2][0]);
      acc[2][1] = fmaf(av.z, bv.y, acc[2][1]);
      acc[3][0] = fmaf(av.w, bv.x, acc[3][0]);
      acc[3][1] = fmaf(av.w, bv.y, acc[3][1]);
    }
  }

#pragma unroll
  for (int i = 0; i < 4; ++i) {
    float2 o; o.x = acc[i][0]; o.y = acc[i][1];
    *(float2*)&G[(size_t)(r0 + ty * 4 + i) * NB2 + n0 + tx * 2] = o;
  }
}

// ---------------------------------------------------------------------------
// k_p: BYTE-IDENTICAL to R9 (strict left-to-right j-sum; trunc(p) boundaries
// are discontinuous so the p-path must stay bit-stable).
// ---------------------------------------------------------------------------
__global__ __launch_bounds__(256) void k_p(const float* __restrict__ G,
    const float* __restrict__ Vp, float* __restrict__ p_out) {
  const int r = blockIdx.x * 256 + threadIdx.x;
  const float* h = G + (size_t)r * NB2 + CQ_;
  float H[PS];
#pragma unroll
  for (int j = 0; j < PS; j += 4) {
    const float4 v = *(const float4*)&h[j];
    H[j + 0] = v.x; H[j + 1] = v.y; H[j + 2] = v.z; H[j + 3] = v.w;
  }
  float s = 0.0f;
#pragma unroll
  for (int j = 0; j < PS; ++j) s += Vp[j] * tanhf(H[j]);   // strict order
  p_out[r] = (float)S_LEN * (1.0f / (1.0f + expf(-s)));
}

// ---------------------------------------------------------------------------
// k_attn: ONE BLOCK (4 waves) PER ROW.
//  Phase A: wave wid computes slots k = 16*step + 4*sub + wid, step=0..6 —
//   7 steps instead of R9's 26 pairs (4x shorter chain), 16-lane stripe dot
//   + 4 subgroup shfl_xor, scores to LDS ss. One barrier.
//  Phase B: each wave REDUNDANTLY computes softmax+gaussian weights from ss
//   (identical results; no extra barrier).
//  Phase C: ballot masks identical in all waves; survivor i processed by
//   wave (i%4); partial float4 accs to LDS; barrier; column-sum write.
// ---------------------------------------------------------------------------
__global__ __launch_bounds__(256, 6) void k_attn(const float* __restrict__ q,
    const float* __restrict__ p_in, const float* __restrict__ G,
    float* __restrict__ out) {
  const int row  = blockIdx.x;
  const int tid  = threadIdx.x;
  const int wid  = tid >> 6;
  const int lane = tid & 63;
  const int b    = row >> 11;

  __shared__ float ss[128];          // scores (101..127 = -inf)
  __shared__ float sacc[4][CQ_];     // per-wave partial output

  const float p  = p_in[row];
  const float tp = truncf(p);
  const float* qb = q + (size_t)b * S_LEN * CQ_;

  const int sub = lane >> 4;          // subgroup 0..3
  const int cb  = (lane & 15) * 16;   // column stripe base

  const float* vrow = G + (size_t)row * NB2 + cb;
  const float4 v0 = *(const float4*)(vrow);
  const float4 v1 = *(const float4*)(vrow + 4);
  const float4 v2 = *(const float4*)(vrow + 8);
  const float4 v3 = *(const float4*)(vrow + 12);

  if (tid >= KW && tid < 128) ss[tid] = -INFINITY;   // slots 101..127

#pragma unroll
  for (int step = 0; step < 7; ++step) {
    const int k = 16 * step + 4 * sub + wid;       // <= 111 < 128
    const float t = p + (float)(k - DH) + 1.0f;    // ref op order
    const int raw = (int)t;                        // trunc toward zero
    const bool ok = (raw >= 1) && (raw <= S_LEN) && (k < KW);
    const float* qr = qb + (size_t)(ok ? raw - 1 : 0) * CQ_ + cb;
    const float4 q0 = *(const float4*)(qr);
    const float4 q1 = *(const float4*)(qr + 4);
    const float4 q2 = *(const float4*)(qr + 8);
    const float4 q3 = *(const float4*)(qr + 12);

    float t0 = q0.x * v0.x, t1 = q1.x * v1.x, t2 = q2.x * v2.x, t3 = q3.x * v3.x;
    t0 = fmaf(q0.y, v0.y, t0); t1 = fmaf(q1.y, v1.y, t1);
    t2 = fmaf(q2.y, v2.y, t2); t3 = fmaf(q3.y, v3.y, t3);
    t0 = fmaf(q0.z, v0.z, t0); t1 = fmaf(q1.z, v1.z, t1);
    t2 = fmaf(q2.z, v2.z, t2); t3 = fmaf(q3.z, v3.z, t3);
    t0 = fmaf(q0.w, v0.w, t0); t1 = fmaf(q1.w, v1.w, t1);
    t2 = fmaf(q2.w, v2.w, t2); t3 = fmaf(q3.w, v3.w, t3);
    float s = (t0 + t1) + (t2 + t3);
    s += __shfl_xor(s, 1, 64);    // reduce inside the 16-lane subgroup
    s += __shfl_xor(s, 2, 64);
    s += __shfl_xor(s, 4, 64);
    s += __shfl_xor(s, 8, 64);
    s = ok ? s : -INFINITY;
    if ((lane & 15) == 0) ss[k] = s;
  }
  __syncthreads();

  // ---- Phase B (redundant per wave, identical results) ----
  const float s0 = ss[lane];
  const float s1 = ss[64 + lane];
  float m = fmaxf(s0, s1);
#pragma unroll
  for (int off = 1; off < 64; off <<= 1) m = fmaxf(m, __shfl_xor(m, off, 64));
  const float e0 = __expf(s0 - m);                  // -inf -> 0
  const float e1 = __expf(s1 - m);
  float den = e0 + e1;
#pragma unroll
  for (int off = 1; off < 64; off <<= 1) den += __shfl_xor(den, off, 64);
  const float inv = 1.0f / den;

  float g0 = ((float)(lane - DH) + tp - p) / (float)DH;        // k = lane
  float g1 = ((float)(lane + (64 - DH)) + tp - p) / (float)DH; // k = 64+lane
  const float w0 = e0 * __expf(-2.0f * g0 * g0) * inv;
  const float w1 = e1 * __expf(-2.0f * g1 * g1) * inv;

  // ---- Phase C: survivors interleaved across waves ----
  unsigned long long m0 = __ballot(w0 > WTH);
  unsigned long long m1 = __ballot((lane < KW - 64) && (w1 > WTH));

  float4 acc = make_float4(0.0f, 0.0f, 0.0f, 0.0f);
  int i = 0;
  while (m0) {
    const int k = __builtin_ctzll(m0);
    m0 &= m0 - 1;
    if ((i & 3) == wid) {                           // wave-uniform
      const float wk = __shfl(w0, k, 64);
      const float t = p + (float)(k - DH) + 1.0f;
      const int r = (int)t - 1;                     // w>0 implies valid
      const float4 qv = *(const float4*)(qb + (size_t)r * CQ_ + lane * 4);
      acc.x = fmaf(wk, qv.x, acc.x);
      acc.y = fmaf(wk, qv.y, acc.y);
      acc.z = fmaf(wk, qv.z, acc.z);
      acc.w = fmaf(wk, qv.w, acc.w);
    }
    ++i;
  }
  while (m1) {
    const int k64 = __builtin_ctzll(m1);
    m1 &= m1 - 1;
    if ((i & 3) == wid) {
      const float wk = __shfl(w1, k64, 64);
      const float t = p + (float)(k64 + (64 - DH)) + 1.0f;
      const int r = (int)t - 1;
      const float4 qv = *(const float4*)(qb + (size_t)r * CQ_ + lane * 4);
      acc.x = fmaf(wk, qv.x, acc.x);
      acc.y = fmaf(wk, qv.y, acc.y);
      acc.z = fmaf(wk, qv.z, acc.z);
      acc.w = fmaf(wk, qv.w, acc.w);
    }
    ++i;
  }
  *(float4*)&sacc[wid][lane * 4] = acc;
  __syncthreads();

  const float r = ((sacc[0][tid] + sacc[1][tid]) + (sacc[2][tid] + sacc[3][tid]));
  out[(size_t)row * CQ_ + tid] = r;
}

// ---------------------------------------------------------------------------
extern "C" void kernel_launch(void* const* d_in, const int* in_sizes, int n_in,
                              void* d_out, int out_size, void* d_ws, size_t ws_size,
                              hipStream_t stream) {
  const float* q  = (const float*)d_in[0];
  const float* ct = (const float*)d_in[1];
  const float* Wa = (const float*)d_in[2];
  const float* Wp = (const float*)d_in[3];
  const float* Vp = (const float*)d_in[4];
  float* out = (float*)d_out;

  // ws (floats): p[4096] | BT[256*384] | G[4096*384]   (~6.7 MB of 268 MB ws)
  float* ws    = (float*)d_ws;
  float* p_ws  = ws;
  float* BT_ws = ws + NB * S_LEN;
  float* G_ws  = BT_ws + (size_t)CC_ * NB2;

  k_prep<<<CC_, NB2, 0, stream>>>(Wa, Wp, BT_ws);
  k_gemm<<<128 * 6, 256, 0, stream>>>(ct, BT_ws, G_ws);
  k_p   <<<(NB * S_LEN) / 256, 256, 0, stream>>>(G_ws, Vp, p_ws);
  k_attn<<<NB * S_LEN, 256, 0, stream>>>(q, p_ws, G_ws, out);
}

// Round 11
// 113.089 us; speedup vs baseline: 1.1433x; 1.1433x over previous
//
#include <hip/hip_runtime.h>
#include <math.h>

#define S_LEN 2048
#define NB    2
#define CQ_   256
#define CC_   256
#define DH    50
#define KW    101
#define PS    100
#define RB    8     // rows per k_align block
#define HPAD  128   // zero-padded hidden width (branch-free loads)
#define WTH   1e-5f // phase-C weight skip threshold

// ---------------------------------------------------------------------------
// k_prep: WpT[c][j] = (j<100) ? Wp[j][c] : 0.   WpT: [256][128] in ws.
// (exact R7 baseline)
// ---------------------------------------------------------------------------
__global__ __launch_bounds__(128) void k_prep(const float* __restrict__ Wp,
                                              float* __restrict__ WpT) {
  const int c = blockIdx.x, j = threadIdx.x;
  WpT[c * HPAD + j] = (j < PS) ? Wp[j * CC_ + c] : 0.0f;
}

// ---------------------------------------------------------------------------
// k_align: exact R7 baseline (best measured config, ~36us by subtraction).
// 384 thr, RB=8, grid 512. tid<256: V column tid; tid>=256: hidden unit.
// Manual 1-quad-ahead rotation; hidden fmaf order BIT-IDENTICAL to R2..R7.
// ---------------------------------------------------------------------------
__global__ __launch_bounds__(384, 3) void k_align(const float* __restrict__ ct,
    const float* __restrict__ Wa, const float* __restrict__ WpT,
    const float* __restrict__ Vp, float* __restrict__ p_out,
    float* __restrict__ V_out) {
  const int r0  = blockIdx.x * RB;
  const int tid = threadIdx.x;
  const float* crow = ct + (size_t)r0 * CC_;   // uniform base

  __shared__ float red[RB][PS + 4];

  if (tid < CQ_) {
    const float* wa = Wa + tid;
    float acc[RB];
#pragma unroll
    for (int r = 0; r < RB; ++r) acc[r] = 0.0f;

    float4 cv0[RB], cv1[RB];
#pragma unroll
    for (int r = 0; r < RB; ++r) cv0[r] = *(const float4*)&crow[r * CC_];
    float w00 = wa[0 * CQ_], w01 = wa[1 * CQ_], w02 = wa[2 * CQ_], w03 = wa[3 * CQ_];

    for (int c = 0; c < CC_ - 4; c += 4) {
      const int cn = c + 4;
#pragma unroll
      for (int r = 0; r < RB; ++r) cv1[r] = *(const float4*)&crow[r * CC_ + cn];
      const float w10 = wa[(size_t)(cn + 0) * CQ_];
      const float w11 = wa[(size_t)(cn + 1) * CQ_];
      const float w12 = wa[(size_t)(cn + 2) * CQ_];
      const float w13 = wa[(size_t)(cn + 3) * CQ_];
#pragma unroll
      for (int r = 0; r < RB; ++r) {
        float t = acc[r];
        t = fmaf(cv0[r].x, w00, t);
        t = fmaf(cv0[r].y, w01, t);
        t = fmaf(cv0[r].z, w02, t);
        t = fmaf(cv0[r].w, w03, t);
        acc[r] = t;
      }
#pragma unroll
      for (int r = 0; r < RB; ++r) cv0[r] = cv1[r];
      w00 = w10; w01 = w11; w02 = w12; w03 = w13;
    }
#pragma unroll
    for (int r = 0; r < RB; ++r) {           // epilogue quad c=252
      float t = acc[r];
      t = fmaf(cv0[r].x, w00, t);
      t = fmaf(cv0[r].y, w01, t);
      t = fmaf(cv0[r].z, w02, t);
      t = fmaf(cv0[r].w, w03, t);
      acc[r] = t;
    }
#pragma unroll
    for (int r = 0; r < RB; ++r)
      V_out[(size_t)(r0 + r) * CQ_ + tid] = acc[r];
  } else {
    const int j = tid - CQ_;
    const float* wh = WpT + j;
    float ah[RB];
#pragma unroll
    for (int r = 0; r < RB; ++r) ah[r] = 0.0f;

    float4 cv0[RB], cv1[RB];
#pragma unroll
    for (int r = 0; r < RB; ++r) cv0[r] = *(const float4*)&crow[r * CC_];
    float w00 = wh[0 * HPAD], w01 = wh[1 * HPAD], w02 = wh[2 * HPAD], w03 = wh[3 * HPAD];

    for (int c = 0; c < CC_ - 4; c += 4) {
      const int cn = c + 4;
#pragma unroll
      for (int r = 0; r < RB; ++r) cv1[r] = *(const float4*)&crow[r * CC_ + cn];
      const float w10 = wh[(size_t)(cn + 0) * HPAD];
      const float w11 = wh[(size_t)(cn + 1) * HPAD];
      const float w12 = wh[(size_t)(cn + 2) * HPAD];
      const float w13 = wh[(size_t)(cn + 3) * HPAD];
#pragma unroll
      for (int r = 0; r < RB; ++r) {
        float t = ah[r];                     // fmaf order x,y,z,w == R2..R7
        t = fmaf(cv0[r].x, w00, t);
        t = fmaf(cv0[r].y, w01, t);
        t = fmaf(cv0[r].z, w02, t);
        t = fmaf(cv0[r].w, w03, t);
        ah[r] = t;
      }
#pragma unroll
      for (int r = 0; r < RB; ++r) cv0[r] = cv1[r];
      w00 = w10; w01 = w11; w02 = w12; w03 = w13;
    }
#pragma unroll
    for (int r = 0; r < RB; ++r) {           // epilogue quad c=252
      float t = ah[r];
      t = fmaf(cv0[r].x, w00, t);
      t = fmaf(cv0[r].y, w01, t);
      t = fmaf(cv0[r].z, w02, t);
      t = fmaf(cv0[r].w, w03, t);
      ah[r] = t;
    }
    if (j < PS) {
      const float vp = Vp[j];
#pragma unroll
      for (int r = 0; r < RB; ++r) red[r][j] = vp * tanhf(ah[r]);
    }
  }
  __syncthreads();
  if (tid < RB) {                         // serial j-sum: identical to R2..R7
    float s = 0.0f;
    for (int j = 0; j < PS; ++j) s += red[tid][j];
    p_out[r0 + tid] = (float)S_LEN * (1.0f / (1.0f + expf(-s)));
  }
}

// ---------------------------------------------------------------------------
// k_attn: R7 baseline with ONE change — phase-A loads are now COALESCED.
// R7's stripe (lane&15)*16 made every load instruction touch 64 distinct
// cache lines (stride-64B per lane); all 16 waves/CU share one TA/L1 pipe.
// New mapping: lane (sub,sl) covers columns {64j + 4sl .. +3, j=0..3} —
// each load covers 4 rows x 256 CONTIGUOUS bytes (16 lines, 4x fewer).
// Subgroup reduction (xor 1,2,4,8) still sums sl=0..15 -> full 256-dot.
// Phase B/C unchanged from R7. V aliases out (row-local read-then-write).
// ---------------------------------------------------------------------------
__global__ __launch_bounds__(256, 4) void k_attn(const float* __restrict__ q,
    const float* __restrict__ p_in, const float* V,   // aliases out
    float* out) {
  const int wid  = threadIdx.x >> 6;
  const int row  = (blockIdx.x << 2) + wid;
  const int lane = threadIdx.x & 63;
  const int b    = row >> 11;

  __shared__ float ss[4][128];   // scores (101..127 = -inf)
  __shared__ float sw[4][128];   // final weights

  const float p  = p_in[row];
  const float tp = truncf(p);
  const float* qb = q + (size_t)b * S_LEN * CQ_;

  const int sub = lane >> 4;          // window-slot within group
  const int sl  = lane & 15;          // subgroup lane
  const int c4  = sl * 4;             // coalesced float4 column offset

  const float* vrow = V + (size_t)row * CQ_;
  const float4 v0 = *(const float4*)(vrow + c4);        // cols   0..63
  const float4 v1 = *(const float4*)(vrow + 64 + c4);   // cols  64..127
  const float4 v2 = *(const float4*)(vrow + 128 + c4);  // cols 128..191
  const float4 v3 = *(const float4*)(vrow + 192 + c4);  // cols 192..255

  if (lane >= KW - 64) ss[wid][64 + lane] = -INFINITY;   // slots 101..127

  for (int g = 0; g < 26; g += 2) {
    const int ka = (g << 2) + sub;                 // uniform per 16-subgroup
    const int kb = ka + 4;
    const float ta = p + (float)(ka - DH) + 1.0f;  // ref op order
    const float tb = p + (float)(kb - DH) + 1.0f;
    const int rawa = (int)ta;                      // trunc toward zero
    const int rawb = (int)tb;
    const bool oka = (rawa >= 1) && (rawa <= S_LEN) && (ka < KW);
    const bool okb = (rawb >= 1) && (rawb <= S_LEN) && (kb < KW);
    const float* qra = qb + (size_t)(oka ? rawa - 1 : 0) * CQ_;
    const float* qrb = qb + (size_t)(okb ? rawb - 1 : 0) * CQ_;

    // 8 loads in flight; each instr: 4 rows x 256B contiguous (16 lines)
    const float4 a0 = *(const float4*)(qra + c4);
    const float4 a1 = *(const float4*)(qra + 64 + c4);
    const float4 a2 = *(const float4*)(qra + 128 + c4);
    const float4 a3 = *(const float4*)(qra + 192 + c4);
    const float4 b0 = *(const float4*)(qrb + c4);
    const float4 b1 = *(const float4*)(qrb + 64 + c4);
    const float4 b2 = *(const float4*)(qrb + 128 + c4);
    const float4 b3 = *(const float4*)(qrb + 192 + c4);

    float t0 = a0.x * v0.x, t1 = a1.x * v1.x, t2 = a2.x * v2.x, t3 = a3.x * v3.x;
    t0 = fmaf(a0.y, v0.y, t0); t1 = fmaf(a1.y, v1.y, t1);
    t2 = fmaf(a2.y, v2.y, t2); t3 = fmaf(a3.y, v3.y, t3);
    t0 = fmaf(a0.z, v0.z, t0); t1 = fmaf(a1.z, v1.z, t1);
    t2 = fmaf(a2.z, v2.z, t2); t3 = fmaf(a3.z, v3.z, t3);
    t0 = fmaf(a0.w, v0.w, t0); t1 = fmaf(a1.w, v1.w, t1);
    t2 = fmaf(a2.w, v2.w, t2); t3 = fmaf(a3.w, v3.w, t3);
    float sA = (t0 + t1) + (t2 + t3);
    sA += __shfl_xor(sA, 1, 64);
    sA += __shfl_xor(sA, 2, 64);
    sA += __shfl_xor(sA, 4, 64);
    sA += __shfl_xor(sA, 8, 64);
    sA = oka ? sA : -INFINITY;
    if (sl == 0) ss[wid][ka] = sA;

    float u0 = b0.x * v0.x, u1 = b1.x * v1.x, u2 = b2.x * v2.x, u3 = b3.x * v3.x;
    u0 = fmaf(b0.y, v0.y, u0); u1 = fmaf(b1.y, v1.y, u1);
    u2 = fmaf(b2.y, v2.y, u2); u3 = fmaf(b3.y, v3.y, u3);
    u0 = fmaf(b0.z, v0.z, u0); u1 = fmaf(b1.z, v1.z, u1);
    u2 = fmaf(b2.z, v2.z, u2); u3 = fmaf(b3.z, v3.z, u3);
    u0 = fmaf(b0.w, v0.w, u0); u1 = fmaf(b1.w, v1.w, u1);
    u2 = fmaf(b2.w, v2.w, u2); u3 = fmaf(b3.w, v3.w, u3);
    float sB = (u0 + u1) + (u2 + u3);
    sB += __shfl_xor(sB, 1, 64);
    sB += __shfl_xor(sB, 2, 64);
    sB += __shfl_xor(sB, 4, 64);
    sB += __shfl_xor(sB, 8, 64);
    sB = okb ? sB : -INFINITY;
    if (sl == 0) ss[wid][kb] = sB;
  }

  const float s0 = ss[wid][lane];
  const float s1 = ss[wid][64 + lane];

  float m = fmaxf(s0, s1);
#pragma unroll
  for (int off = 1; off < 64; off <<= 1) m = fmaxf(m, __shfl_xor(m, off, 64));

  const float e0 = __expf(s0 - m);                  // -inf -> 0
  const float e1 = __expf(s1 - m);
  float den = e0 + e1;
#pragma unroll
  for (int off = 1; off < 64; off <<= 1) den += __shfl_xor(den, off, 64);
  const float inv = 1.0f / den;

  float g0 = ((float)(lane - DH) + tp - p) / (float)DH;        // k = lane
  float g1 = ((float)(lane + (64 - DH)) + tp - p) / (float)DH; // k = 64+lane
  const float w0 = e0 * __expf(-2.0f * g0 * g0) * inv;
  const float w1 = e1 * __expf(-2.0f * g1 * g1) * inv;
  sw[wid][lane] = w0;
  if (lane < KW - 64) sw[wid][64 + lane] = w1;
  // wave-private LDS rows: intra-wave lgkmcnt ordering suffices

  // ---- Phase C: batch-4 survivor walk (ascending k order preserved) ----
  unsigned long long m0 = __ballot(w0 > WTH);
  unsigned long long m1 = __ballot((lane < KW - 64) && (w1 > WTH));

  float4 acc = make_float4(0.0f, 0.0f, 0.0f, 0.0f);
  while ((m0 | m1) != 0ull) {
    int kk[4];
#pragma unroll
    for (int i = 0; i < 4; ++i) {
      int k = -1;
      if (m0)      { k = __builtin_ctzll(m0);      m0 &= m0 - 1; }
      else if (m1) { k = 64 + __builtin_ctzll(m1); m1 &= m1 - 1; }
      kk[i] = k;
    }
#pragma unroll
    for (int i = 0; i < 4; ++i) {
      if (kk[i] >= 0) {                             // wave-uniform
        const float wk = sw[wid][kk[i]];
        const float t = p + (float)(kk[i] - DH) + 1.0f;
        const int r = (int)t - 1;                   // w>0 implies valid
        const float4 qv = *(const float4*)(qb + (size_t)r * CQ_ + lane * 4);
        acc.x = fmaf(wk, qv.x, acc.x);
        acc.y = fmaf(wk, qv.y, acc.y);
        acc.z = fmaf(wk, qv.z, acc.z);
        acc.w = fmaf(wk, qv.w, acc.w);
      }
    }
  }
  *(float4*)(out + (size_t)row * CQ_ + lane * 4) = acc;
}

// ---------------------------------------------------------------------------
extern "C" void kernel_launch(void* const* d_in, const int* in_sizes, int n_in,
                              void* d_out, int out_size, void* d_ws, size_t ws_size,
                              hipStream_t stream) {
  const float* q  = (const float*)d_in[0];
  const float* ct = (const float*)d_in[1];
  const float* Wa = (const float*)d_in[2];
  const float* Wp = (const float*)d_in[3];
  const float* Vp = (const float*)d_in[4];
  float* out = (float*)d_out;

  // ws (floats): p[4096] | WpT[256*128]  -> 147 KB
  float* ws     = (float*)d_ws;
  float* p_ws   = ws;
  float* WpT_ws = ws + NB * S_LEN;

  k_prep <<<CC_, HPAD, 0, stream>>>(Wp, WpT_ws);
  k_align<<<(NB * S_LEN) / RB, 384, 0, stream>>>(ct, Wa, WpT_ws, Vp, p_ws, out);
  k_attn <<<(NB * S_LEN) / 4, 256, 0, stream>>>(q, p_ws, out, out);
}